// Round 3
// baseline (347.318 us; speedup 1.0000x reference)
//
#include <hip/hip_runtime.h>

#define B_  2
#define S_  2048
#define D_  1024
#define H_  16
#define DH_ 64
#define BH_ (B_*H_)
#define NT_ (S_/64)

using f32x4   = __attribute__((ext_vector_type(4))) float;
using short4v = __attribute__((ext_vector_type(4))) short;
using short8v = __attribute__((ext_vector_type(8))) short;

// Proj outputs (bf16): q*32 and k pre-split hi/lo, [bh][s][dh]; v transposed [bh][dh][s].
__device__ short g_qh[(size_t)BH_*S_*DH_];
__device__ short g_ql[(size_t)BH_*S_*DH_];
__device__ short g_kh[(size_t)BH_*S_*DH_];
__device__ short g_kl[(size_t)BH_*S_*DH_];
__device__ short g_vt[(size_t)BH_*DH_*S_];

__device__ __forceinline__ short f2bf(float x){
  unsigned u = __builtin_bit_cast(unsigned, x);
  u += 0x7fffu + ((u >> 16) & 1u);           // RNE
  return (short)(unsigned short)(u >> 16);
}
__device__ __forceinline__ float bf2f(short h){
  return __builtin_bit_cast(float, ((unsigned)(unsigned short)h) << 16);
}
__device__ __forceinline__ void split4f(const float4 v, short4v& h4, short4v& l4){
  float f[4] = {v.x, v.y, v.z, v.w};
#pragma unroll
  for (int i = 0; i < 4; ++i){
    short hh = f2bf(f[i]);
    h4[i] = hh;
    l4[i] = f2bf(f[i] - bf2f(hh));
  }
}

#define MFMA16(A,B,C) __builtin_amdgcn_mfma_f32_16x16x32_bf16((A),(B),(C),0,0,0)

// ---------------------------------------------------------------------------
// QKV projection.  128x128 tile, 4 waves, BK=32, split-bf16 (3-term) for Q/K
// blocks, plain bf16 (1-term) for V blocks. Outputs bf16 per layouts above.
// ---------------------------------------------------------------------------
__global__ __launch_bounds__(256) void qkv_proj_mfma(
    const float* __restrict__ X, const float* __restrict__ W,
    const float* __restrict__ bias)
{
  __shared__ short AH[128][40], AL[128][40], BHs[128][40], BLs[128][40];

  const int tid = threadIdx.x;
  const int w  = tid >> 6;
  const int ln = tid & 15;
  const int g  = (tid & 63) >> 4;
  const int wr = w >> 1, wc = w & 1;
  const int m0 = blockIdx.y * 128;
  const int n0 = blockIdx.x * 128;
  const int which = n0 >> 10;       // 0=q 1=k 2=v (block-uniform)

  f32x4 zero4 = {0.f, 0.f, 0.f, 0.f};
  f32x4 acc[4][4];
#pragma unroll
  for (int mf = 0; mf < 4; ++mf)
#pragma unroll
    for (int nf = 0; nf < 4; ++nf) acc[mf][nf] = zero4;

  for (int k0 = 0; k0 < D_; k0 += 32) {
#pragma unroll
    for (int rep = 0; rep < 4; ++rep) {
      int idx = rep * 256 + tid;
      int r  = idx >> 3;
      int c4 = (idx & 7) << 2;
      float4 a = *(const float4*)&X[(size_t)(m0 + r) * D_ + k0 + c4];
      float4 b = *(const float4*)&W[(size_t)(n0 + r) * D_ + k0 + c4];
      short4v ah4, al4, bh4, bl4;
      split4f(a, ah4, al4);
      split4f(b, bh4, bl4);
      *(short4v*)&AH [r][c4] = ah4;
      *(short4v*)&BHs[r][c4] = bh4;
      if (which < 2) {
        *(short4v*)&AL [r][c4] = al4;
        *(short4v*)&BLs[r][c4] = bl4;
      }
    }
    __syncthreads();

    short8v ah[4], al[4], bhf[4], blf[4];
#pragma unroll
    for (int mf = 0; mf < 4; ++mf) {
      ah[mf] = *(const short8v*)&AH[64*wr + 16*mf + ln][8*g];
      if (which < 2) al[mf] = *(const short8v*)&AL[64*wr + 16*mf + ln][8*g];
    }
#pragma unroll
    for (int nf = 0; nf < 4; ++nf) {
      bhf[nf] = *(const short8v*)&BHs[64*wc + 16*nf + ln][8*g];
      if (which < 2) blf[nf] = *(const short8v*)&BLs[64*wc + 16*nf + ln][8*g];
    }
#pragma unroll
    for (int mf = 0; mf < 4; ++mf)
#pragma unroll
      for (int nf = 0; nf < 4; ++nf) {
        acc[mf][nf] = MFMA16(ah[mf], bhf[nf], acc[mf][nf]);
        if (which < 2) {
          acc[mf][nf] = MFMA16(al[mf], bhf[nf], acc[mf][nf]);
          acc[mf][nf] = MFMA16(ah[mf], blf[nf], acc[mf][nf]);
        }
      }
    __syncthreads();
  }

  // Epilogue. D layout: row=(lane>>4)*4+reg, col=lane&15.
#pragma unroll
  for (int nf = 0; nf < 4; ++nf) {
    int col = n0 + 64*wc + 16*nf + ln;
    float bb = bias[col];
    int hh = (col & 1023) >> 6;
    int dh = col & 63;
#pragma unroll
    for (int mf = 0; mf < 4; ++mf) {
      int row0 = m0 + 64*wr + 16*mf + 4*g;
      int bidx = row0 >> 11;
      int s0   = row0 & 2047;
      int bh   = bidx * H_ + hh;
      if (which == 2) {
        short4v v4;
#pragma unroll
        for (int i = 0; i < 4; ++i) v4[i] = f2bf(acc[mf][nf][i] + bb);
        *(short4v*)&g_vt[((size_t)bh * DH_ + dh) * S_ + s0] = v4;
      } else {
        short* dH = (which == 0) ? g_qh : g_kh;
        short* dL = (which == 0) ? g_ql : g_kl;
        float sc  = (which == 0) ? 32.0f : 1.0f;
#pragma unroll
        for (int i = 0; i < 4; ++i) {
          float v = (acc[mf][nf][i] + bb) * sc;
          short hi = f2bf(v);
          short lo = f2bf(v - bf2f(hi));
          size_t o = ((size_t)bh * S_ + s0 + i) * DH_ + dh;
          dH[o] = hi;
          dL[o] = lo;
        }
      }
    }
  }
}

// ---------------------------------------------------------------------------
// Flash attention. Block = 128 q-rows x (b,h); 4 waves x 32 rows; no barriers.
// K/V fragments read directly from global (L1/L2-resident, ~24KB per tile).
// P staged per-wave in XOR-swizzled LDS. Online softmax in fp32.
// ---------------------------------------------------------------------------
__global__ __launch_bounds__(256, 2) void attn_mfma(float* __restrict__ out)
{
  __shared__ short PS[4][32][64];   // per-wave, XOR-swizzled rows

  const int tid = threadIdx.x;
  const int w  = tid >> 6;
  const int ln = tid & 15;
  const int g  = (tid & 63) >> 4;

  // XCD-chunked swizzle: 512 blocks, XCD x gets bh in [4x,4x+4), all q-tiles.
  const int bid = blockIdx.x;
  const int swz = (bid & 7) * 64 + (bid >> 3);
  const int bh  = swz >> 4;
  const int q0  = (swz & 15) * 128;
  const int b   = bh >> 4, h = bh & 15;

  const size_t qb = (size_t)bh * S_ * DH_;
  const short* __restrict__ Kh = g_kh + qb;
  const short* __restrict__ Kl = g_kl + qb;
  const short* __restrict__ Vt = g_vt + (size_t)bh * DH_ * S_;

  // Q fragments: rows q0+32w+16rf+ln, k-slots d = 32ks+8g+j.
  short8v qh[2][2], ql[2][2];
#pragma unroll
  for (int rf = 0; rf < 2; ++rf)
#pragma unroll
    for (int ks = 0; ks < 2; ++ks) {
      size_t o = qb + (size_t)(q0 + 32*w + 16*rf + ln) * DH_ + 32*ks + 8*g;
      qh[rf][ks] = *(const short8v*)&g_qh[o];
      ql[rf][ks] = *(const short8v*)&g_ql[o];
    }

  f32x4 zero4 = {0.f,0.f,0.f,0.f};
  f32x4 o_[2][4];
  float m_[2][4], l_[2][4];
#pragma unroll
  for (int rf = 0; rf < 2; ++rf)
#pragma unroll
    for (int i = 0; i < 4; ++i) {
      o_[rf][i&3] = o_[rf][i&3];  // no-op to appease unroll; real init below
    }
#pragma unroll
  for (int rf = 0; rf < 2; ++rf)
#pragma unroll
    for (int nf = 0; nf < 4; ++nf) o_[rf][nf] = zero4;
#pragma unroll
  for (int rf = 0; rf < 2; ++rf)
#pragma unroll
    for (int i = 0; i < 4; ++i) { m_[rf][i] = -1e30f; l_[rf][i] = 0.f; }

  for (int t = 0; t < NT_; ++t) {
    const int t0 = t * 64;

    // ---- K fragments (hi/lo), issued as a batch so loads overlap MFMA ----
    short8v kh[2][4], kl[2][4];
#pragma unroll
    for (int ks = 0; ks < 2; ++ks)
#pragma unroll
      for (int nf = 0; nf < 4; ++nf) {
        size_t o = (size_t)(t0 + 16*nf + ln) * DH_ + 32*ks + 8*g;
        kh[ks][nf] = *(const short8v*)&Kh[o];
        kl[ks][nf] = *(const short8v*)&Kl[o];
      }

    // ---- S = Q K^T (x32 folded into Q), 3-term split ----
    f32x4 s[2][4];
#pragma unroll
    for (int rf = 0; rf < 2; ++rf)
#pragma unroll
      for (int nf = 0; nf < 4; ++nf) s[rf][nf] = zero4;
#pragma unroll
    for (int rf = 0; rf < 2; ++rf)
#pragma unroll
      for (int ks = 0; ks < 2; ++ks)
#pragma unroll
        for (int nf = 0; nf < 4; ++nf) {
          s[rf][nf] = MFMA16(qh[rf][ks], kh[ks][nf], s[rf][nf]);
          s[rf][nf] = MFMA16(ql[rf][ks], kh[ks][nf], s[rf][nf]);
          s[rf][nf] = MFMA16(qh[rf][ks], kl[ks][nf], s[rf][nf]);
        }

    // ---- V fragments: issue before softmax so latency hides under VALU ----
    short8v vb[2][4];
#pragma unroll
    for (int ks = 0; ks < 2; ++ks)
#pragma unroll
      for (int nf = 0; nf < 4; ++nf)
        vb[ks][nf] = *(const short8v*)&Vt[(size_t)(16*nf + ln) * S_ + t0 + 32*ks + 8*g];

    // ---- online softmax; rows = 16rf+4g+i, cols = 16nf+ln ----
#pragma unroll
    for (int rf = 0; rf < 2; ++rf)
#pragma unroll
      for (int i = 0; i < 4; ++i) {
        float mt = fmaxf(fmaxf(s[rf][0][i], s[rf][1][i]),
                         fmaxf(s[rf][2][i], s[rf][3][i]));
        mt = fmaxf(mt, __shfl_xor(mt, 1));
        mt = fmaxf(mt, __shfl_xor(mt, 2));
        mt = fmaxf(mt, __shfl_xor(mt, 4));
        mt = fmaxf(mt, __shfl_xor(mt, 8));
        float mn = fmaxf(m_[rf][i], mt);
        float corr = __expf(m_[rf][i] - mn);
        float sum = 0.f;
#pragma unroll
        for (int nf = 0; nf < 4; ++nf) {
          float p = __expf(s[rf][nf][i] - mn);
          sum += p;
          s[rf][nf][i] = p;
        }
        sum += __shfl_xor(sum, 1);
        sum += __shfl_xor(sum, 2);
        sum += __shfl_xor(sum, 4);
        sum += __shfl_xor(sum, 8);
        l_[rf][i] = l_[rf][i] * corr + sum;
        m_[rf][i] = mn;
        const int row = 16*rf + 4*g + i;
        const int e   = (4*g + i) & 7;
#pragma unroll
        for (int nf = 0; nf < 4; ++nf) {
          o_[rf][nf][i] *= corr;
          PS[w][row][(16*nf + ln) ^ (e << 3)] = f2bf(s[rf][nf][i]);
        }
      }

    // ---- O += P V ----
#pragma unroll
    for (int rf = 0; rf < 2; ++rf)
#pragma unroll
      for (int ks = 0; ks < 2; ++ks) {
        const short8v pa =
            *(const short8v*)&PS[w][16*rf + ln][(32*ks + 8*g) ^ ((ln & 7) << 3)];
#pragma unroll
        for (int nf = 0; nf < 4; ++nf)
          o_[rf][nf] = MFMA16(pa, vb[ks][nf], o_[rf][nf]);
      }
  }

  // ---- epilogue ----
#pragma unroll
  for (int rf = 0; rf < 2; ++rf)
#pragma unroll
    for (int i = 0; i < 4; ++i) {
      float inv = 1.0f / l_[rf][i];
      int row = q0 + 32*w + 16*rf + 4*g + i;
      float* op = &out[((size_t)b * S_ + row) * D_ + h * DH_];
#pragma unroll
      for (int nf = 0; nf < 4; ++nf)
        op[16*nf + ln] = o_[rf][nf][i] * inv;
    }
}

extern "C" void kernel_launch(void* const* d_in, const int* in_sizes, int n_in,
                              void* d_out, int out_size, void* d_ws, size_t ws_size,
                              hipStream_t stream) {
    (void)d_ws; (void)ws_size; (void)n_in; (void)in_sizes;
    const float* X    = (const float*)d_in[0];  // query [B,S,D]
    const float* W    = (const float*)d_in[3];  // [3D, D]
    const float* bias = (const float*)d_in[4];  // [3D]
    float* out = (float*)d_out;

    dim3 gProj(24, 32);        // N/128 x M/128
    qkv_proj_mfma<<<gProj, 256, 0, stream>>>(X, W, bias);

    attn_mfma<<<dim3(512), 256, 0, stream>>>(out);
}

// Round 4
// 318.328 us; speedup vs baseline: 1.0911x; 1.0911x over previous
//
#include <hip/hip_runtime.h>

#define B_  2
#define S_  2048
#define D_  1024
#define H_  16
#define DH_ 64
#define BH_ (B_*H_)
#define NT_ (S_/64)

using f32x4   = __attribute__((ext_vector_type(4))) float;
using short4v = __attribute__((ext_vector_type(4))) short;
using short8v = __attribute__((ext_vector_type(8))) short;

// Proj outputs (bf16): q*32 and k pre-split hi/lo, [bh][s][dh]; v transposed [bh][dh][s].
__device__ short g_qh[(size_t)BH_*S_*DH_];
__device__ short g_ql[(size_t)BH_*S_*DH_];
__device__ short g_kh[(size_t)BH_*S_*DH_];
__device__ short g_kl[(size_t)BH_*S_*DH_];
__device__ short g_vt[(size_t)BH_*DH_*S_];

__device__ __forceinline__ short f2bf(float x){
  unsigned u = __builtin_bit_cast(unsigned, x);
  u += 0x7fffu + ((u >> 16) & 1u);           // RNE
  return (short)(unsigned short)(u >> 16);
}
__device__ __forceinline__ float bf2f(short h){
  return __builtin_bit_cast(float, ((unsigned)(unsigned short)h) << 16);
}
__device__ __forceinline__ void split4f(const float4 v, short4v& h4, short4v& l4){
  float f[4] = {v.x, v.y, v.z, v.w};
#pragma unroll
  for (int i = 0; i < 4; ++i){
    short hh = f2bf(f[i]);
    h4[i] = hh;
    l4[i] = f2bf(f[i] - bf2f(hh));
  }
}

#define MFMA16(A,B,C) __builtin_amdgcn_mfma_f32_16x16x32_bf16((A),(B),(C),0,0,0)

// ---------------------------------------------------------------------------
// QKV projection.  128x128 tile, 4 waves, BK=32, split-bf16 (3-term) for Q/K
// blocks, plain bf16 (1-term) for V blocks.
// Staging is register-double-buffered (loads for k+1 issue before MFMA of k).
// Epilogue re-stages C through LDS for fully-coalesced 16B global stores.
// ---------------------------------------------------------------------------
__global__ __launch_bounds__(256) void qkv_proj_mfma(
    const float* __restrict__ X, const float* __restrict__ W,
    const float* __restrict__ bias)
{
  __shared__ short SM[20480];   // 40 KB, aliased below
  short (*AH )[40] = (short(*)[40])(SM);
  short (*AL )[40] = (short(*)[40])(SM + 5120);
  short (*BHs)[40] = (short(*)[40])(SM + 10240);
  short (*BLs)[40] = (short(*)[40])(SM + 15360);
  short *LT = SM;               // epilogue transpose buffer, pitch 136, 128 rows

  const int tid = threadIdx.x;
  const int w  = tid >> 6;
  const int ln = tid & 15;
  const int g  = (tid & 63) >> 4;
  const int wr = w >> 1, wc = w & 1;
  const int m0 = blockIdx.y * 128;
  const int n0 = blockIdx.x * 128;
  const int which = n0 >> 10;       // 0=q 1=k 2=v (block-uniform)

  f32x4 zero4 = {0.f, 0.f, 0.f, 0.f};
  f32x4 acc[4][4];
#pragma unroll
  for (int mf = 0; mf < 4; ++mf)
#pragma unroll
    for (int nf = 0; nf < 4; ++nf) acc[mf][nf] = zero4;

  float4 xa[4], wb[4];
#pragma unroll
  for (int rep = 0; rep < 4; ++rep) {
    int idx = rep * 256 + tid;
    int r  = idx >> 3;
    int c4 = (idx & 7) << 2;
    xa[rep] = *(const float4*)&X[(size_t)(m0 + r) * D_ + c4];
    wb[rep] = *(const float4*)&W[(size_t)(n0 + r) * D_ + c4];
  }

  for (int k0 = 0; k0 < D_; k0 += 32) {
    // split current regs -> LDS
#pragma unroll
    for (int rep = 0; rep < 4; ++rep) {
      int idx = rep * 256 + tid;
      int r  = idx >> 3;
      int c4 = (idx & 7) << 2;
      short4v ah4, al4, bh4, bl4;
      split4f(xa[rep], ah4, al4);
      split4f(wb[rep], bh4, bl4);
      *(short4v*)&AH [r][c4] = ah4;
      *(short4v*)&BHs[r][c4] = bh4;
      if (which < 2) {
        *(short4v*)&AL [r][c4] = al4;
        *(short4v*)&BLs[r][c4] = bl4;
      }
    }
    __syncthreads();

    // prefetch next K-step while MFMA below runs
    if (k0 + 32 < D_) {
#pragma unroll
      for (int rep = 0; rep < 4; ++rep) {
        int idx = rep * 256 + tid;
        int r  = idx >> 3;
        int c4 = (idx & 7) << 2;
        xa[rep] = *(const float4*)&X[(size_t)(m0 + r) * D_ + k0 + 32 + c4];
        wb[rep] = *(const float4*)&W[(size_t)(n0 + r) * D_ + k0 + 32 + c4];
      }
    }

    short8v ah[4], al[4], bhf[4], blf[4];
#pragma unroll
    for (int mf = 0; mf < 4; ++mf) {
      ah[mf] = *(const short8v*)&AH[64*wr + 16*mf + ln][8*g];
      if (which < 2) al[mf] = *(const short8v*)&AL[64*wr + 16*mf + ln][8*g];
    }
#pragma unroll
    for (int nf = 0; nf < 4; ++nf) {
      bhf[nf] = *(const short8v*)&BHs[64*wc + 16*nf + ln][8*g];
      if (which < 2) blf[nf] = *(const short8v*)&BLs[64*wc + 16*nf + ln][8*g];
    }
#pragma unroll
    for (int mf = 0; mf < 4; ++mf)
#pragma unroll
      for (int nf = 0; nf < 4; ++nf) {
        acc[mf][nf] = MFMA16(ah[mf], bhf[nf], acc[mf][nf]);
        if (which < 2) {
          acc[mf][nf] = MFMA16(al[mf], bhf[nf], acc[mf][nf]);
          acc[mf][nf] = MFMA16(ah[mf], blf[nf], acc[mf][nf]);
        }
      }
    __syncthreads();
  }

  // ---- epilogue: bias+scale into acc, then LDS-transpose coalesced stores ----
  const float sc = (which == 0) ? 32.0f : 1.0f;
  float bb[4];
#pragma unroll
  for (int nf = 0; nf < 4; ++nf) bb[nf] = bias[n0 + 64*wc + 16*nf + ln];
#pragma unroll
  for (int mf = 0; mf < 4; ++mf)
#pragma unroll
    for (int nf = 0; nf < 4; ++nf)
#pragma unroll
      for (int i = 0; i < 4; ++i)
        acc[mf][nf][i] = (acc[mf][nf][i] + bb[nf]) * sc;

  const int bidx  = m0 >> 11;
  const int s0    = m0 & 2047;
  const int hbase = (n0 & 1023) >> 6;

  if (which == 2) {
    // V: LT as [dh_local(128)][s_local(128)], then linear stores to g_vt.
#pragma unroll
    for (int nf = 0; nf < 4; ++nf) {
      int dl = 64*wc + 16*nf + ln;
#pragma unroll
      for (int mf = 0; mf < 4; ++mf) {
        int sl = 64*wr + 16*mf + 4*g;
        short4v v4;
#pragma unroll
        for (int i = 0; i < 4; ++i) v4[i] = f2bf(acc[mf][nf][i]);
        *(short4v*)&LT[dl*136 + sl] = v4;
      }
    }
    __syncthreads();
#pragma unroll
    for (int rep = 0; rep < 8; ++rep) {
      int idx = rep * 256 + tid;
      int r  = idx >> 4;          // dh_local
      int sg = idx & 15;
      short8v v = *(const short8v*)&LT[r*136 + sg*8];
      int h = hbase + (r >> 6), dh = r & 63;
      *(short8v*)&g_vt[(((size_t)(bidx*H_ + h))*DH_ + dh)*S_ + s0 + sg*8] = v;
    }
  } else {
    short* dH = (which == 0) ? g_qh : g_kh;
    short* dL = (which == 0) ? g_ql : g_kl;
    // pass A: hi. LT as [s_local(128)][dh_local(128)].
#pragma unroll
    for (int mf = 0; mf < 4; ++mf)
#pragma unroll
      for (int nf = 0; nf < 4; ++nf) {
        int dl = 64*wc + 16*nf + ln;
#pragma unroll
        for (int i = 0; i < 4; ++i)
          LT[(64*wr + 16*mf + 4*g + i)*136 + dl] = f2bf(acc[mf][nf][i]);
      }
    __syncthreads();
#pragma unroll
    for (int rep = 0; rep < 8; ++rep) {
      int idx = rep * 256 + tid;
      int r  = idx >> 4;          // s row
      int sg = idx & 15;
      short8v v = *(const short8v*)&LT[r*136 + sg*8];
      int h = hbase + (sg >> 3);
      int dh = (sg & 7) * 8;
      *(short8v*)&dH[(((size_t)(bidx*H_ + h))*S_ + s0 + r)*DH_ + dh] = v;
    }
    __syncthreads();
    // pass B: lo = f2bf(v - bf2f(hi))
#pragma unroll
    for (int mf = 0; mf < 4; ++mf)
#pragma unroll
      for (int nf = 0; nf < 4; ++nf) {
        int dl = 64*wc + 16*nf + ln;
#pragma unroll
        for (int i = 0; i < 4; ++i) {
          float v = acc[mf][nf][i];
          short hi = f2bf(v);
          LT[(64*wr + 16*mf + 4*g + i)*136 + dl] = f2bf(v - bf2f(hi));
        }
      }
    __syncthreads();
#pragma unroll
    for (int rep = 0; rep < 8; ++rep) {
      int idx = rep * 256 + tid;
      int r  = idx >> 4;
      int sg = idx & 15;
      short8v v = *(const short8v*)&LT[r*136 + sg*8];
      int h = hbase + (sg >> 3);
      int dh = (sg & 7) * 8;
      *(short8v*)&dL[(((size_t)(bidx*H_ + h))*S_ + s0 + r)*DH_ + dh] = v;
    }
  }
}

// ---------------------------------------------------------------------------
// Flash attention. Block = 128 q-rows x (b,h); 4 waves x 32 rows; no barriers.
// K/V fragments read directly from global (L1/L2-resident, ~24KB per tile).
// P staged per-wave in XOR-swizzled LDS. Online softmax in fp32.
// ---------------------------------------------------------------------------
__global__ __launch_bounds__(256, 2) void attn_mfma(float* __restrict__ out)
{
  __shared__ short PS[4][32][64];   // per-wave, XOR-swizzled rows

  const int tid = threadIdx.x;
  const int w  = tid >> 6;
  const int ln = tid & 15;
  const int g  = (tid & 63) >> 4;

  // XCD-chunked swizzle: 512 blocks, XCD x gets bh in [4x,4x+4), all q-tiles.
  const int bid = blockIdx.x;
  const int swz = (bid & 7) * 64 + (bid >> 3);
  const int bh  = swz >> 4;
  const int q0  = (swz & 15) * 128;
  const int b   = bh >> 4, h = bh & 15;

  const size_t qb = (size_t)bh * S_ * DH_;
  const short* __restrict__ Kh = g_kh + qb;
  const short* __restrict__ Kl = g_kl + qb;
  const short* __restrict__ Vt = g_vt + (size_t)bh * DH_ * S_;

  // Q fragments: rows q0+32w+16rf+ln, k-slots d = 32ks+8g+j.
  short8v qh[2][2], ql[2][2];
#pragma unroll
  for (int rf = 0; rf < 2; ++rf)
#pragma unroll
    for (int ks = 0; ks < 2; ++ks) {
      size_t o = qb + (size_t)(q0 + 32*w + 16*rf + ln) * DH_ + 32*ks + 8*g;
      qh[rf][ks] = *(const short8v*)&g_qh[o];
      ql[rf][ks] = *(const short8v*)&g_ql[o];
    }

  f32x4 zero4 = {0.f,0.f,0.f,0.f};
  f32x4 o_[2][4];
  float m_[2][4], l_[2][4];
#pragma unroll
  for (int rf = 0; rf < 2; ++rf)
#pragma unroll
    for (int nf = 0; nf < 4; ++nf) o_[rf][nf] = zero4;
#pragma unroll
  for (int rf = 0; rf < 2; ++rf)
#pragma unroll
    for (int i = 0; i < 4; ++i) { m_[rf][i] = -1e30f; l_[rf][i] = 0.f; }

  for (int t = 0; t < NT_; ++t) {
    const int t0 = t * 64;

    // ---- K fragments (hi/lo), issued as a batch so loads overlap MFMA ----
    short8v kh[2][4], kl[2][4];
#pragma unroll
    for (int ks = 0; ks < 2; ++ks)
#pragma unroll
      for (int nf = 0; nf < 4; ++nf) {
        size_t o = (size_t)(t0 + 16*nf + ln) * DH_ + 32*ks + 8*g;
        kh[ks][nf] = *(const short8v*)&Kh[o];
        kl[ks][nf] = *(const short8v*)&Kl[o];
      }

    // ---- S = Q K^T (x32 folded into Q), 3-term split ----
    f32x4 s[2][4];
#pragma unroll
    for (int rf = 0; rf < 2; ++rf)
#pragma unroll
      for (int nf = 0; nf < 4; ++nf) s[rf][nf] = zero4;
#pragma unroll
    for (int rf = 0; rf < 2; ++rf)
#pragma unroll
      for (int ks = 0; ks < 2; ++ks)
#pragma unroll
        for (int nf = 0; nf < 4; ++nf) {
          s[rf][nf] = MFMA16(qh[rf][ks], kh[ks][nf], s[rf][nf]);
          s[rf][nf] = MFMA16(ql[rf][ks], kh[ks][nf], s[rf][nf]);
          s[rf][nf] = MFMA16(qh[rf][ks], kl[ks][nf], s[rf][nf]);
        }

    // ---- V fragments: issue before softmax so latency hides under VALU ----
    short8v vb[2][4];
#pragma unroll
    for (int ks = 0; ks < 2; ++ks)
#pragma unroll
      for (int nf = 0; nf < 4; ++nf)
        vb[ks][nf] = *(const short8v*)&Vt[(size_t)(16*nf + ln) * S_ + t0 + 32*ks + 8*g];

    // ---- online softmax; rows = 16rf+4g+i, cols = 16nf+ln ----
#pragma unroll
    for (int rf = 0; rf < 2; ++rf)
#pragma unroll
      for (int i = 0; i < 4; ++i) {
        float mt = fmaxf(fmaxf(s[rf][0][i], s[rf][1][i]),
                         fmaxf(s[rf][2][i], s[rf][3][i]));
        mt = fmaxf(mt, __shfl_xor(mt, 1));
        mt = fmaxf(mt, __shfl_xor(mt, 2));
        mt = fmaxf(mt, __shfl_xor(mt, 4));
        mt = fmaxf(mt, __shfl_xor(mt, 8));
        float mn = fmaxf(m_[rf][i], mt);
        float corr = __expf(m_[rf][i] - mn);
        float sum = 0.f;
#pragma unroll
        for (int nf = 0; nf < 4; ++nf) {
          float p = __expf(s[rf][nf][i] - mn);
          sum += p;
          s[rf][nf][i] = p;
        }
        sum += __shfl_xor(sum, 1);
        sum += __shfl_xor(sum, 2);
        sum += __shfl_xor(sum, 4);
        sum += __shfl_xor(sum, 8);
        l_[rf][i] = l_[rf][i] * corr + sum;
        m_[rf][i] = mn;
        const int row = 16*rf + 4*g + i;
        const int e   = (4*g + i) & 7;
#pragma unroll
        for (int nf = 0; nf < 4; ++nf) {
          o_[rf][nf][i] *= corr;
          PS[w][row][(16*nf + ln) ^ (e << 3)] = f2bf(s[rf][nf][i]);
        }
      }

    // ---- O += P V ----
#pragma unroll
    for (int rf = 0; rf < 2; ++rf)
#pragma unroll
      for (int ks = 0; ks < 2; ++ks) {
        const short8v pa =
            *(const short8v*)&PS[w][16*rf + ln][(32*ks + 8*g) ^ ((ln & 7) << 3)];
#pragma unroll
        for (int nf = 0; nf < 4; ++nf)
          o_[rf][nf] = MFMA16(pa, vb[ks][nf], o_[rf][nf]);
      }
  }

  // ---- epilogue ----
#pragma unroll
  for (int rf = 0; rf < 2; ++rf)
#pragma unroll
    for (int i = 0; i < 4; ++i) {
      float inv = 1.0f / l_[rf][i];
      int row = q0 + 32*w + 16*rf + 4*g + i;
      float* op = &out[((size_t)b * S_ + row) * D_ + h * DH_];
#pragma unroll
      for (int nf = 0; nf < 4; ++nf)
        op[16*nf + ln] = o_[rf][nf][i] * inv;
    }
}

extern "C" void kernel_launch(void* const* d_in, const int* in_sizes, int n_in,
                              void* d_out, int out_size, void* d_ws, size_t ws_size,
                              hipStream_t stream) {
    (void)d_ws; (void)ws_size; (void)n_in; (void)in_sizes;
    const float* X    = (const float*)d_in[0];  // query [B,S,D]
    const float* W    = (const float*)d_in[3];  // [3D, D]
    const float* bias = (const float*)d_in[4];  // [3D]
    float* out = (float*)d_out;

    dim3 gProj(24, 32);        // N/128 x M/128
    qkv_proj_mfma<<<gProj, 256, 0, stream>>>(X, W, bias);

    attn_mfma<<<dim3(512), 256, 0, stream>>>(out);
}